// Round 1
// baseline (579.497 us; speedup 1.0000x reference)
//
#include <hip/hip_runtime.h>
#include <hip/hip_bf16.h>

// Problem constants
#define B_ 4
#define T_ 200
#define U_ 100
#define ENC_DIM 512
#define JDIM 640
#define VOCAB 1024
#define M_TOTAL (B_*T_*U_)   // 80000

typedef __attribute__((ext_vector_type(8))) short short8;
typedef __attribute__((ext_vector_type(4))) float float4v;
typedef __attribute__((ext_vector_type(4))) unsigned short ushort4v;

__device__ __forceinline__ unsigned short f2bf(float x) {
    unsigned u = __builtin_bit_cast(unsigned, x);
    u += 0x7fffu + ((u >> 16) & 1u);   // round-to-nearest-even
    return (unsigned short)(u >> 16);
}

__device__ __forceinline__ float fast_tanh(float x) {
    return 1.0f - 2.0f / (__expf(2.0f * x) + 1.0f);
}

__device__ __forceinline__ void gload_lds16(const void* g, void* l) {
    __builtin_amdgcn_global_load_lds(
        (const __attribute__((address_space(1))) unsigned int*)g,
        (__attribute__((address_space(3))) unsigned int*)l, 16, 0, 0);
}

// ---------------------------------------------------------------------------
// Projection: Y[M,640] = X[M,512] @ W[512,640] (+ bias). 16x64 tiles, fp32.
// 16-row tiles -> 2x the blocks of the old 32-row version: ~3 blocks/CU
// (12 waves/CU) instead of ~1 block/CU -> latency actually hidden.
// ---------------------------------------------------------------------------
#define PBM 16
#define PBN 64
#define PBK 32

__global__ __launch_bounds__(256)
void proj_tiled(const float* __restrict__ X, const float* __restrict__ W,
                const float* __restrict__ bias, float* __restrict__ Y, int M) {
    __shared__ float Xs[PBM][PBK + 4];   // [16][36]
    __shared__ float Ws[PBK][PBN + 4];   // [32][68]
    const int tid = threadIdx.x;
    const int row0 = blockIdx.x * PBM;
    const int col0 = blockIdx.y * PBN;

    const int xr = tid >> 3;          // 0..15 (X stage row, threads 0..127)
    const int xk = (tid & 7) * 4;     // X stage k chunk
    const int wk = tid >> 4;          // 0..15 (W stage k, +16)
    const int wn = (tid & 15) * 4;    // W stage n chunk

    const int ty = tid >> 4;          // 0..15 output row
    const int tx = tid & 15;          // output col group (x4)

    int xrow = row0 + xr; if (xrow >= M) xrow = M - 1;

    float4v acc = {0.f, 0.f, 0.f, 0.f};

    for (int k0 = 0; k0 < ENC_DIM; k0 += PBK) {
        if (tid < 128)
            *(float4v*)&Xs[xr][xk] = *(const float4v*)(X + (size_t)xrow * ENC_DIM + k0 + xk);
        #pragma unroll
        for (int i = 0; i < 2; ++i)
            *(float4v*)&Ws[wk + i*16][wn] =
                *(const float4v*)(W + (size_t)(k0 + wk + i*16) * JDIM + col0 + wn);
        __syncthreads();
        #pragma unroll
        for (int k = 0; k < PBK; ++k) {
            float a = Xs[ty][k];
            float4v w = *(const float4v*)&Ws[k][tx * 4];
            acc += w * a;
        }
        __syncthreads();
    }

    float4v bb = {0.f,0.f,0.f,0.f};
    if (bias) bb = *(const float4v*)(bias + col0 + tx * 4);
    int r0 = row0 + ty;
    if (r0 < M) *(float4v*)(Y + (size_t)r0 * JDIM + col0 + tx*4) = acc + bb;
}

// ---------------------------------------------------------------------------
// Transpose + cast: Wt[n][k] = bf16(W_out[k][n]).  W_out: [640,1024]
// ---------------------------------------------------------------------------
__global__ __launch_bounds__(256)
void transpose_cast(const float* __restrict__ W, unsigned short* __restrict__ Wt) {
    __shared__ float tile[32][33];
    const int bk = blockIdx.x;   // 0..19
    const int bn = blockIdx.y;   // 0..31
    const int tx = threadIdx.x;  // 0..31
    const int ty = threadIdx.y;  // 0..7
    #pragma unroll
    for (int i = 0; i < 32; i += 8)
        tile[ty + i][tx] = W[(bk * 32 + ty + i) * VOCAB + bn * 32 + tx];
    __syncthreads();
    #pragma unroll
    for (int i = 0; i < 32; i += 8)
        Wt[(bn * 32 + ty + i) * JDIM + bk * 32 + tx] = f2bf(tile[tx][ty + i]);
}

// ---------------------------------------------------------------------------
// joint_tanh: jbuf[m-m0][k] = bf16(tanh(encp[row(m)][k] + predp[row(m)][k]))
// ---------------------------------------------------------------------------
__global__ __launch_bounds__(256)
void joint_tanh(const float* __restrict__ encp, const float* __restrict__ predp,
                unsigned short* __restrict__ jbuf, int m0, int mcount) {
    int idx = blockIdx.x * 256 + threadIdx.x;
    if (idx >= mcount * (JDIM / 4)) return;
    int m  = idx / (JDIM / 4);
    int c4 = (idx - m * (JDIM / 4)) * 4;
    int mg = m0 + m;
    int b   = mg / (T_ * U_);
    int rem = mg - b * (T_ * U_);
    int t   = rem / U_;
    int u   = rem - t * U_;
    float4v e = *(const float4v*)(encp  + (size_t)(b * T_ + t) * JDIM + c4);
    float4v p = *(const float4v*)(predp + (size_t)(b * U_ + u) * JDIM + c4);
    ushort4v v;
    v.x = f2bf(fast_tanh(e.x + p.x));
    v.y = f2bf(fast_tanh(e.y + p.y));
    v.z = f2bf(fast_tanh(e.z + p.z));
    v.w = f2bf(fast_tanh(e.w + p.w));
    *(ushort4v*)(jbuf + (size_t)m * JDIM + c4) = v;
}

// ---------------------------------------------------------------------------
// Pure bf16 GEMM, m97 structure: out = A @ Wt^T + b_out
// A: [mc,640] bf16 k-contig.  Wt: [1024,640] bf16 k-contig.
// BM=BN=128, BK=128 (5 K-iters: half the barrier drains of BK=64),
// 256 thr (2x2 waves, 4x4 frags), global_load_lds w=16.
// Grid is 1D, bn-fastest, XCD-swizzled: the 8 bn-blocks sharing an A row-tile
// run adjacent on ONE XCD -> A-tile read once from HBM, 7x from that L2.
// Output stores are nontemporal: 327 MB streamed once, keep L2/L3 for A/Wt.
// ---------------------------------------------------------------------------
#define GBM 128
#define GBN 128
#define GBK 128
#define NBN (VOCAB / GBN)    // 8  (== #XCDs, and grid.x always % 8 == 0)

__global__ __launch_bounds__(256, 2)
void gemm_joint(const unsigned short* __restrict__ A,
                const unsigned short* __restrict__ Wt,
                const float* __restrict__ bout,
                float* __restrict__ out)
{
    __shared__ __align__(16) unsigned short As[GBM * GBK];  // 32 KB
    __shared__ __align__(16) unsigned short Bs[GBN * GBK];  // 32 KB

    const int tid = threadIdx.x;

    // XCD-aware swizzle (bijective: gridDim.x = nbm*8, always % 8 == 0).
    // bid%8 = XCD -> each XCD owns a contiguous tile range; within it,
    // bn cycles fastest so A-tile sharers are temporally adjacent.
    const int cpx = gridDim.x >> 3;
    const int bid = blockIdx.x;
    const int swz = (bid & 7) * cpx + (bid >> 3);
    const int bm = swz >> 3;          // NBN == 8
    const int bn = swz & (NBN - 1);

    // staging: thread covers row (tid>>4)+16i, k-chunk (tid&15)*8
    // LDS dst bytes = tid*16 + i*4096  (lane-linear: gload_lds requirement)
    const int srow = tid >> 4;        // 0..15
    const int scol = (tid & 15) * 8;  // 0..120
    const unsigned short* aBase = A  + (size_t)(bm * GBM + srow) * JDIM + scol;
    const unsigned short* bBase = Wt + (size_t)(bn * GBN + srow) * JDIM + scol;
    unsigned short* asDst = &As[srow * GBK + scol];
    unsigned short* bsDst = &Bs[srow * GBK + scol];

    const int wave = tid >> 6, lane = tid & 63;
    const int wm = (wave >> 1) * 64, wn = (wave & 1) * 64;
    const int lm = lane & 15, quad = lane >> 4;

    float4v acc[4][4];
    #pragma unroll
    for (int i = 0; i < 4; ++i)
        #pragma unroll
        for (int j = 0; j < 4; ++j)
            acc[i][j] = (float4v){0.f, 0.f, 0.f, 0.f};

    for (int k0 = 0; k0 < JDIM; k0 += GBK) {   // 5 iterations
        #pragma unroll
        for (int i = 0; i < 8; ++i) {
            gload_lds16(aBase + (size_t)(i * 16) * JDIM + k0, asDst + i * 16 * GBK);
            gload_lds16(bBase + (size_t)(i * 16) * JDIM + k0, bsDst + i * 16 * GBK);
        }
        __syncthreads();

        #pragma unroll
        for (int kk = 0; kk < GBK; kk += 32) {
            short8 a[4], b[4];
            #pragma unroll
            for (int i = 0; i < 4; ++i)
                a[i] = *(const short8*)(&As[(wm + i * 16 + lm) * GBK + kk + quad * 8]);
            #pragma unroll
            for (int j = 0; j < 4; ++j)
                b[j] = *(const short8*)(&Bs[(wn + j * 16 + lm) * GBK + kk + quad * 8]);
            #pragma unroll
            for (int i = 0; i < 4; ++i)
                #pragma unroll
                for (int j = 0; j < 4; ++j)
                    acc[i][j] = __builtin_amdgcn_mfma_f32_16x16x32_bf16(a[i], b[j], acc[i][j], 0, 0, 0);
        }
        __syncthreads();
    }

    #pragma unroll
    for (int j = 0; j < 4; ++j) {
        int ng = bn * GBN + wn + j * 16 + lm;
        float bias = bout[ng];
        #pragma unroll
        for (int i = 0; i < 4; ++i) {
            int mg0 = bm * GBM + wm + i * 16 + quad * 4;
            #pragma unroll
            for (int r = 0; r < 4; ++r)
                __builtin_nontemporal_store(acc[i][j][r] + bias,
                                            out + (size_t)(mg0 + r) * VOCAB + ng);
        }
    }
}

// ---------------------------------------------------------------------------
// Fallback (ws too small): round-1 fused kernel — tanh recomputed per N-tile.
// ---------------------------------------------------------------------------
#define BM 128
#define BN 128
#define BK 64
#define LDST 72

__global__ __launch_bounds__(256, 2)
void joint_gemm_fused(const float* __restrict__ encp, const float* __restrict__ predp,
                      const unsigned short* __restrict__ Wt, const float* __restrict__ bout,
                      float* __restrict__ out)
{
    __shared__ __align__(16) unsigned short As[BM * LDST];
    __shared__ __align__(16) unsigned short Bs[BN * LDST];
    const int tid = threadIdx.x;
    const int bm = blockIdx.x, bn = blockIdx.y;
    const int rbase = tid >> 4;
    const int c4 = (tid & 15) * 4;
    int encOff[8], predOff[8];
    #pragma unroll
    for (int i = 0; i < 8; ++i) {
        int mg  = bm * BM + i * 16 + rbase;
        int b   = mg / (T_ * U_);
        int rem = mg - b * (T_ * U_);
        int t   = rem / U_;
        int u   = rem - t * U_;
        encOff[i]  = (b * T_ + t) * JDIM + c4;
        predOff[i] = (b * U_ + u) * JDIM + c4;
    }
    const int nrow = tid >> 3;
    const int bk8  = (tid & 7) * 8;
    const size_t wtBase = (size_t)(bn * BN) * JDIM;
    const int wave = tid >> 6, lane = tid & 63;
    const int wm = (wave >> 1) * 64, wn = (wave & 1) * 64;
    const int lm = lane & 15, quad = lane >> 4;

    float4v acc[4][4];
    #pragma unroll
    for (int i = 0; i < 4; ++i)
        #pragma unroll
        for (int j = 0; j < 4; ++j)
            acc[i][j] = (float4v){0.f, 0.f, 0.f, 0.f};

    for (int k0 = 0; k0 < JDIM; k0 += BK) {
        #pragma unroll
        for (int i = 0; i < 8; ++i) {
            int row = i * 16 + rbase;
            float4v e4 = *(const float4v*)(encp + encOff[i] + k0);
            float4v p4 = *(const float4v*)(predp + predOff[i] + k0);
            ushort4v v;
            v.x = f2bf(fast_tanh(e4.x + p4.x));
            v.y = f2bf(fast_tanh(e4.y + p4.y));
            v.z = f2bf(fast_tanh(e4.z + p4.z));
            v.w = f2bf(fast_tanh(e4.w + p4.w));
            *(ushort4v*)(&As[row * LDST + c4]) = v;
        }
        #pragma unroll
        for (int i = 0; i < 4; ++i) {
            int n = i * 32 + nrow;
            float4v w = *(const float4v*)((const float*)(Wt + wtBase + (size_t)n * JDIM + k0 + bk8));
            *(float4v*)(&Bs[n * LDST + bk8]) = w;
        }
        __syncthreads();
        #pragma unroll
        for (int kk = 0; kk < BK; kk += 32) {
            short8 a[4], b[4];
            #pragma unroll
            for (int i = 0; i < 4; ++i)
                a[i] = *(const short8*)(&As[(wm + i * 16 + lm) * LDST + kk + quad * 8]);
            #pragma unroll
            for (int j = 0; j < 4; ++j)
                b[j] = *(const short8*)(&Bs[(wn + j * 16 + lm) * LDST + kk + quad * 8]);
            #pragma unroll
            for (int i = 0; i < 4; ++i)
                #pragma unroll
                for (int j = 0; j < 4; ++j)
                    acc[i][j] = __builtin_amdgcn_mfma_f32_16x16x32_bf16(a[i], b[j], acc[i][j], 0, 0, 0);
        }
        __syncthreads();
    }
    #pragma unroll
    for (int j = 0; j < 4; ++j) {
        int ng = bn * BN + wn + j * 16 + lm;
        float bias = bout[ng];
        #pragma unroll
        for (int i = 0; i < 4; ++i) {
            int mg0 = bm * BM + wm + i * 16 + quad * 4;
            #pragma unroll
            for (int r = 0; r < 4; ++r)
                out[(size_t)(mg0 + r) * VOCAB + ng] = acc[i][j][r] + bias;
        }
    }
}

// ---------------------------------------------------------------------------
extern "C" void kernel_launch(void* const* d_in, const int* in_sizes, int n_in,
                              void* d_out, int out_size, void* d_ws, size_t ws_size,
                              hipStream_t stream) {
    const float* enc_out  = (const float*)d_in[0];  // [4,200,512]
    const float* pred_out = (const float*)d_in[1];  // [4,100,512]
    const float* W_enc    = (const float*)d_in[2];  // [512,640]
    const float* b_enc    = (const float*)d_in[3];  // [640]
    const float* W_pred   = (const float*)d_in[4];  // [512,640]
    const float* W_out    = (const float*)d_in[5];  // [640,1024]
    const float* b_out    = (const float*)d_in[6];  // [1024]
    float* out = (float*)d_out;

    float* encp  = (float*)d_ws;                                 // 800*640 fp32
    float* predp = encp + 800 * JDIM;                            // 400*640 fp32
    unsigned short* Wt = (unsigned short*)(predp + 400 * JDIM);  // 1024*640 bf16
    unsigned short* jbuf = Wt + (size_t)VOCAB * JDIM;            // chunked joint bf16

    const size_t fixedBytes = (800 * JDIM + 400 * JDIM) * sizeof(float)
                            + (size_t)VOCAB * JDIM * sizeof(unsigned short);

    proj_tiled<<<dim3(800 / PBM, 10), 256, 0, stream>>>(enc_out, W_enc, b_enc, encp, 800);
    proj_tiled<<<dim3(400 / PBM, 10), 256, 0, stream>>>(pred_out, W_pred, nullptr, predp, 400);
    transpose_cast<<<dim3(20, 32), dim3(32, 8), 0, stream>>>(W_out, Wt);

    size_t avail = ws_size > fixedBytes ? ws_size - fixedBytes : 0;
    long mcMax = (long)(avail / (JDIM * sizeof(unsigned short)));
    mcMax = (mcMax / 128) * 128;
    if (mcMax > M_TOTAL) mcMax = M_TOTAL;

    if (mcMax >= 8192) {
        for (int m0 = 0; m0 < M_TOTAL; m0 += (int)mcMax) {
            int mc = M_TOTAL - m0 < mcMax ? M_TOTAL - m0 : (int)mcMax;  // always mult of 128
            int nThreadsChunks = mc * (JDIM / 4);
            joint_tanh<<<(nThreadsChunks + 255) / 256, 256, 0, stream>>>(encp, predp, jbuf, m0, mc);
            gemm_joint<<<dim3((mc / GBM) * NBN), 256, 0, stream>>>(jbuf, Wt, b_out,
                                                                   out + (size_t)m0 * VOCAB);
        }
    } else {
        // scratch too small for materialization — round-1 fused path
        joint_gemm_fused<<<dim3(M_TOTAL / BM, VOCAB / BN), 256, 0, stream>>>(encp, predp, Wt, b_out, out);
    }
}

// Round 3
// 484.441 us; speedup vs baseline: 1.1962x; 1.1962x over previous
//
#include <hip/hip_runtime.h>
#include <hip/hip_bf16.h>

// Problem constants
#define B_ 4
#define T_ 200
#define U_ 100
#define ENC_DIM 512
#define JDIM 640
#define VOCAB 1024
#define M_TOTAL (B_*T_*U_)   // 80000

typedef __attribute__((ext_vector_type(8))) short short8;
typedef __attribute__((ext_vector_type(4))) float float4v;
typedef __attribute__((ext_vector_type(4))) unsigned short ushort4v;
typedef __attribute__((ext_vector_type(8))) unsigned short ushort8v;

__device__ __forceinline__ unsigned short f2bf(float x) {
    unsigned u = __builtin_bit_cast(unsigned, x);
    u += 0x7fffu + ((u >> 16) & 1u);   // round-to-nearest-even
    return (unsigned short)(u >> 16);
}

__device__ __forceinline__ float fast_tanh(float x) {
    return 1.0f - 2.0f / (__expf(2.0f * x) + 1.0f);
}

__device__ __forceinline__ void gload_lds16(const void* g, void* l) {
    __builtin_amdgcn_global_load_lds(
        (const __attribute__((address_space(1))) unsigned int*)g,
        (__attribute__((address_space(3))) unsigned int*)l, 16, 0, 0);
}

// ---------------------------------------------------------------------------
// Projection: Y[M,640] = X[M,512] @ W[512,640] (+ bias). 16x64 tiles, fp32.
// ---------------------------------------------------------------------------
#define PBM 16
#define PBN 64
#define PBK 32

__global__ __launch_bounds__(256)
void proj_tiled(const float* __restrict__ X, const float* __restrict__ W,
                const float* __restrict__ bias, float* __restrict__ Y, int M) {
    __shared__ float Xs[PBM][PBK + 4];   // [16][36]
    __shared__ float Ws[PBK][PBN + 4];   // [32][68]
    const int tid = threadIdx.x;
    const int row0 = blockIdx.x * PBM;
    const int col0 = blockIdx.y * PBN;

    const int xr = tid >> 3;          // 0..15 (X stage row, threads 0..127)
    const int xk = (tid & 7) * 4;     // X stage k chunk
    const int wk = tid >> 4;          // 0..15 (W stage k, +16)
    const int wn = (tid & 15) * 4;    // W stage n chunk

    const int ty = tid >> 4;          // 0..15 output row
    const int tx = tid & 15;          // output col group (x4)

    int xrow = row0 + xr; if (xrow >= M) xrow = M - 1;

    float4v acc = {0.f, 0.f, 0.f, 0.f};

    for (int k0 = 0; k0 < ENC_DIM; k0 += PBK) {
        if (tid < 128)
            *(float4v*)&Xs[xr][xk] = *(const float4v*)(X + (size_t)xrow * ENC_DIM + k0 + xk);
        #pragma unroll
        for (int i = 0; i < 2; ++i)
            *(float4v*)&Ws[wk + i*16][wn] =
                *(const float4v*)(W + (size_t)(k0 + wk + i*16) * JDIM + col0 + wn);
        __syncthreads();
        #pragma unroll
        for (int k = 0; k < PBK; ++k) {
            float a = Xs[ty][k];
            float4v w = *(const float4v*)&Ws[k][tx * 4];
            acc += w * a;
        }
        __syncthreads();
    }

    float4v bb = {0.f,0.f,0.f,0.f};
    if (bias) bb = *(const float4v*)(bias + col0 + tx * 4);
    int r0 = row0 + ty;
    if (r0 < M) *(float4v*)(Y + (size_t)r0 * JDIM + col0 + tx*4) = acc + bb;
}

// ---------------------------------------------------------------------------
// Transpose + cast: Wt[n][k] = bf16(W_out[k][n]).  W_out: [640,1024]
// ---------------------------------------------------------------------------
__global__ __launch_bounds__(256)
void transpose_cast(const float* __restrict__ W, unsigned short* __restrict__ Wt) {
    __shared__ float tile[32][33];
    const int bk = blockIdx.x;   // 0..19
    const int bn = blockIdx.y;   // 0..31
    const int tx = threadIdx.x;  // 0..31
    const int ty = threadIdx.y;  // 0..7
    #pragma unroll
    for (int i = 0; i < 32; i += 8)
        tile[ty + i][tx] = W[(bk * 32 + ty + i) * VOCAB + bn * 32 + tx];
    __syncthreads();
    #pragma unroll
    for (int i = 0; i < 32; i += 8)
        Wt[(bn * 32 + ty + i) * JDIM + bk * 32 + tx] = f2bf(tile[tx][ty + i]);
}

// ---------------------------------------------------------------------------
// joint_tanh: jbuf[m-m0][k] = bf16(tanh(encp[row(m)][k] + predp[row(m)][k]))
// 8 elems/thread, 16 B stores (G13).
// ---------------------------------------------------------------------------
__global__ __launch_bounds__(256)
void joint_tanh(const float* __restrict__ encp, const float* __restrict__ predp,
                unsigned short* __restrict__ jbuf, int m0, int mcount) {
    int idx = blockIdx.x * 256 + threadIdx.x;
    if (idx >= mcount * (JDIM / 8)) return;
    int m  = idx / (JDIM / 8);
    int c8 = (idx - m * (JDIM / 8)) * 8;
    int mg = m0 + m;
    int b   = mg / (T_ * U_);
    int rem = mg - b * (T_ * U_);
    int t   = rem / U_;
    int u   = rem - t * U_;
    const float* eRow = encp  + (size_t)(b * T_ + t) * JDIM + c8;
    const float* pRow = predp + (size_t)(b * U_ + u) * JDIM + c8;
    float4v e0 = *(const float4v*)(eRow);
    float4v e1 = *(const float4v*)(eRow + 4);
    float4v p0 = *(const float4v*)(pRow);
    float4v p1 = *(const float4v*)(pRow + 4);
    ushort8v v;
    v.s0 = f2bf(fast_tanh(e0.x + p0.x));
    v.s1 = f2bf(fast_tanh(e0.y + p0.y));
    v.s2 = f2bf(fast_tanh(e0.z + p0.z));
    v.s3 = f2bf(fast_tanh(e0.w + p0.w));
    v.s4 = f2bf(fast_tanh(e1.x + p1.x));
    v.s5 = f2bf(fast_tanh(e1.y + p1.y));
    v.s6 = f2bf(fast_tanh(e1.z + p1.z));
    v.s7 = f2bf(fast_tanh(e1.w + p1.w));
    *(ushort8v*)(jbuf + (size_t)m * JDIM + c8) = v;
}

// ---------------------------------------------------------------------------
// Pure bf16 GEMM: out = A @ Wt^T + b_out
// A: [mc,640] bf16 k-contig.  Wt: [1024,640] bf16 k-contig.
// BM=BN=128, BK=128, 256 thr (2x2 waves, 4x4 frags), global_load_lds w=16.
//
// T2 bank-conflict fix (rule #21: both-sides-or-neither with gload_lds):
//   LDS dest stays lane-linear (tid*16 B per 4 KB stripe) — required by HW.
//   GLOBAL source is pre-swizzled: lane (tid&15) fetches 16B-chunk
//   ((tid&15) ^ (srow&7)) of its row; row&7 invariant under +16 row stripes.
//   Read side applies the same XOR: phys chunk = ((kk>>3)+quad) ^ (lm&7).
//   => per quad group the 16 lanes span all 32 banks (2 lanes/bank = free)
//   instead of 16-way on one 4-bank slot (row stride 256 B ≡ bank 0).
// ---------------------------------------------------------------------------
#define GBM 128
#define GBN 128
#define GBK 128
#define NBN (VOCAB / GBN)    // 8

__global__ __launch_bounds__(256, 2)
void gemm_joint(const unsigned short* __restrict__ A,
                const unsigned short* __restrict__ Wt,
                const float* __restrict__ bout,
                float* __restrict__ out)
{
    __shared__ __align__(16) unsigned short As[GBM * GBK];  // 32 KB
    __shared__ __align__(16) unsigned short Bs[GBN * GBK];  // 32 KB

    const int tid = threadIdx.x;

    // XCD-aware swizzle (bijective: gridDim.x = nbm*8, always % 8 == 0).
    const int cpx = gridDim.x >> 3;
    const int bid = blockIdx.x;
    const int swz = (bid & 7) * cpx + (bid >> 3);
    const int bm = swz >> 3;          // NBN == 8
    const int bn = swz & (NBN - 1);

    // staging: thread covers row (tid>>4)+16i; LDS dst = tid*16B + i*4KB (linear)
    const int srow = tid >> 4;        // 0..15
    const int schunk = tid & 15;      // 16B chunk slot in LDS
    const int scolSwz = (schunk ^ (srow & 7)) * 8;   // pre-swizzled global chunk
    const unsigned short* aBase = A  + (size_t)(bm * GBM + srow) * JDIM + scolSwz;
    const unsigned short* bBase = Wt + (size_t)(bn * GBN + srow) * JDIM + scolSwz;
    unsigned short* asDst = &As[srow * GBK + schunk * 8];
    unsigned short* bsDst = &Bs[srow * GBK + schunk * 8];

    const int wave = tid >> 6, lane = tid & 63;
    const int wm = (wave >> 1) * 64, wn = (wave & 1) * 64;
    const int lm = lane & 15, quad = lane >> 4;
    const int rx = lm & 7;            // row&7 for this lane's fragment rows

    float4v acc[4][4];
    #pragma unroll
    for (int i = 0; i < 4; ++i)
        #pragma unroll
        for (int j = 0; j < 4; ++j)
            acc[i][j] = (float4v){0.f, 0.f, 0.f, 0.f};

    for (int k0 = 0; k0 < JDIM; k0 += GBK) {   // 5 iterations
        #pragma unroll
        for (int i = 0; i < 8; ++i) {
            gload_lds16(aBase + (size_t)(i * 16) * JDIM + k0, asDst + i * 16 * GBK);
            gload_lds16(bBase + (size_t)(i * 16) * JDIM + k0, bsDst + i * 16 * GBK);
        }
        __syncthreads();

        #pragma unroll
        for (int kk = 0; kk < GBK; kk += 32) {
            const int cp = (((kk >> 3) + quad) ^ rx) * 8;   // swizzled k-offset (shorts)
            short8 a[4], b[4];
            #pragma unroll
            for (int i = 0; i < 4; ++i)
                a[i] = *(const short8*)(&As[(wm + i * 16 + lm) * GBK + cp]);
            #pragma unroll
            for (int j = 0; j < 4; ++j)
                b[j] = *(const short8*)(&Bs[(wn + j * 16 + lm) * GBK + cp]);
            #pragma unroll
            for (int i = 0; i < 4; ++i)
                #pragma unroll
                for (int j = 0; j < 4; ++j)
                    acc[i][j] = __builtin_amdgcn_mfma_f32_16x16x32_bf16(a[i], b[j], acc[i][j], 0, 0, 0);
        }
        __syncthreads();
    }

    #pragma unroll
    for (int j = 0; j < 4; ++j) {
        int ng = bn * GBN + wn + j * 16 + lm;
        float bias = bout[ng];
        #pragma unroll
        for (int i = 0; i < 4; ++i) {
            int mg0 = bm * GBM + wm + i * 16 + quad * 4;
            #pragma unroll
            for (int r = 0; r < 4; ++r)
                __builtin_nontemporal_store(acc[i][j][r] + bias,
                                            out + (size_t)(mg0 + r) * VOCAB + ng);
        }
    }
}

// ---------------------------------------------------------------------------
// Fallback (ws too small): round-1 fused kernel — tanh recomputed per N-tile.
// ---------------------------------------------------------------------------
#define BM 128
#define BN 128
#define BK 64
#define LDST 72

__global__ __launch_bounds__(256, 2)
void joint_gemm_fused(const float* __restrict__ encp, const float* __restrict__ predp,
                      const unsigned short* __restrict__ Wt, const float* __restrict__ bout,
                      float* __restrict__ out)
{
    __shared__ __align__(16) unsigned short As[BM * LDST];
    __shared__ __align__(16) unsigned short Bs[BN * LDST];
    const int tid = threadIdx.x;
    const int bm = blockIdx.x, bn = blockIdx.y;
    const int rbase = tid >> 4;
    const int c4 = (tid & 15) * 4;
    int encOff[8], predOff[8];
    #pragma unroll
    for (int i = 0; i < 8; ++i) {
        int mg  = bm * BM + i * 16 + rbase;
        int b   = mg / (T_ * U_);
        int rem = mg - b * (T_ * U_);
        int t   = rem / U_;
        int u   = rem - t * U_;
        encOff[i]  = (b * T_ + t) * JDIM + c4;
        predOff[i] = (b * U_ + u) * JDIM + c4;
    }
    const int nrow = tid >> 3;
    const int bk8  = (tid & 7) * 8;
    const size_t wtBase = (size_t)(bn * BN) * JDIM;
    const int wave = tid >> 6, lane = tid & 63;
    const int wm = (wave >> 1) * 64, wn = (wave & 1) * 64;
    const int lm = lane & 15, quad = lane >> 4;

    float4v acc[4][4];
    #pragma unroll
    for (int i = 0; i < 4; ++i)
        #pragma unroll
        for (int j = 0; j < 4; ++j)
            acc[i][j] = (float4v){0.f, 0.f, 0.f, 0.f};

    for (int k0 = 0; k0 < JDIM; k0 += BK) {
        #pragma unroll
        for (int i = 0; i < 8; ++i) {
            int row = i * 16 + rbase;
            float4v e4 = *(const float4v*)(encp + encOff[i] + k0);
            float4v p4 = *(const float4v*)(predp + predOff[i] + k0);
            ushort4v v;
            v.x = f2bf(fast_tanh(e4.x + p4.x));
            v.y = f2bf(fast_tanh(e4.y + p4.y));
            v.z = f2bf(fast_tanh(e4.z + p4.z));
            v.w = f2bf(fast_tanh(e4.w + p4.w));
            *(ushort4v*)(&As[row * LDST + c4]) = v;
        }
        #pragma unroll
        for (int i = 0; i < 4; ++i) {
            int n = i * 32 + nrow;
            float4v w = *(const float4v*)((const float*)(Wt + wtBase + (size_t)n * JDIM + k0 + bk8));
            *(float4v*)(&Bs[n * LDST + bk8]) = w;
        }
        __syncthreads();
        #pragma unroll
        for (int kk = 0; kk < BK; kk += 32) {
            short8 a[4], b[4];
            #pragma unroll
            for (int i = 0; i < 4; ++i)
                a[i] = *(const short8*)(&As[(wm + i * 16 + lm) * LDST + kk + quad * 8]);
            #pragma unroll
            for (int j = 0; j < 4; ++j)
                b[j] = *(const short8*)(&Bs[(wn + j * 16 + lm) * LDST + kk + quad * 8]);
            #pragma unroll
            for (int i = 0; i < 4; ++i)
                #pragma unroll
                for (int j = 0; j < 4; ++j)
                    acc[i][j] = __builtin_amdgcn_mfma_f32_16x16x32_bf16(a[i], b[j], acc[i][j], 0, 0, 0);
        }
        __syncthreads();
    }
    #pragma unroll
    for (int j = 0; j < 4; ++j) {
        int ng = bn * BN + wn + j * 16 + lm;
        float bias = bout[ng];
        #pragma unroll
        for (int i = 0; i < 4; ++i) {
            int mg0 = bm * BM + wm + i * 16 + quad * 4;
            #pragma unroll
            for (int r = 0; r < 4; ++r)
                out[(size_t)(mg0 + r) * VOCAB + ng] = acc[i][j][r] + bias;
        }
    }
}

// ---------------------------------------------------------------------------
extern "C" void kernel_launch(void* const* d_in, const int* in_sizes, int n_in,
                              void* d_out, int out_size, void* d_ws, size_t ws_size,
                              hipStream_t stream) {
    const float* enc_out  = (const float*)d_in[0];  // [4,200,512]
    const float* pred_out = (const float*)d_in[1];  // [4,100,512]
    const float* W_enc    = (const float*)d_in[2];  // [512,640]
    const float* b_enc    = (const float*)d_in[3];  // [640]
    const float* W_pred   = (const float*)d_in[4];  // [512,640]
    const float* W_out    = (const float*)d_in[5];  // [640,1024]
    const float* b_out    = (const float*)d_in[6];  // [1024]
    float* out = (float*)d_out;

    float* encp  = (float*)d_ws;                                 // 800*640 fp32
    float* predp = encp + 800 * JDIM;                            // 400*640 fp32
    unsigned short* Wt = (unsigned short*)(predp + 400 * JDIM);  // 1024*640 bf16
    unsigned short* jbuf = Wt + (size_t)VOCAB * JDIM;            // chunked joint bf16

    const size_t fixedBytes = (800 * JDIM + 400 * JDIM) * sizeof(float)
                            + (size_t)VOCAB * JDIM * sizeof(unsigned short);

    proj_tiled<<<dim3(800 / PBM, 10), 256, 0, stream>>>(enc_out, W_enc, b_enc, encp, 800);
    proj_tiled<<<dim3(400 / PBM, 10), 256, 0, stream>>>(pred_out, W_pred, nullptr, predp, 400);
    transpose_cast<<<dim3(20, 32), dim3(32, 8), 0, stream>>>(W_out, Wt);

    size_t avail = ws_size > fixedBytes ? ws_size - fixedBytes : 0;
    long mcMax = (long)(avail / (JDIM * sizeof(unsigned short)));
    mcMax = (mcMax / 128) * 128;
    if (mcMax > M_TOTAL) mcMax = M_TOTAL;

    if (mcMax >= 8192) {
        for (int m0 = 0; m0 < M_TOTAL; m0 += (int)mcMax) {
            int mc = M_TOTAL - m0 < mcMax ? M_TOTAL - m0 : (int)mcMax;  // always mult of 128
            int nThreads = mc * (JDIM / 8);
            joint_tanh<<<(nThreads + 255) / 256, 256, 0, stream>>>(encp, predp, jbuf, m0, mc);
            gemm_joint<<<dim3((mc / GBM) * NBN), 256, 0, stream>>>(jbuf, Wt, b_out,
                                                                   out + (size_t)m0 * VOCAB);
        }
    } else {
        // scratch too small for materialization — round-1 fused path
        joint_gemm_fused<<<dim3(M_TOTAL / BM, VOCAB / BN), 256, 0, stream>>>(encp, predp, Wt, b_out, out);
    }
}

// Round 4
// 464.286 us; speedup vs baseline: 1.2481x; 1.0434x over previous
//
#include <hip/hip_runtime.h>
#include <hip/hip_bf16.h>

// Problem constants
#define B_ 4
#define T_ 200
#define U_ 100
#define ENC_DIM 512
#define JDIM 640
#define VOCAB 1024
#define M_TOTAL (B_*T_*U_)   // 80000

typedef __attribute__((ext_vector_type(8))) short short8;
typedef __attribute__((ext_vector_type(4))) float float4v;
typedef __attribute__((ext_vector_type(4))) unsigned short ushort4v;
typedef __attribute__((ext_vector_type(8))) unsigned short ushort8v;

__device__ __forceinline__ unsigned short f2bf(float x) {
    unsigned u = __builtin_bit_cast(unsigned, x);
    u += 0x7fffu + ((u >> 16) & 1u);   // round-to-nearest-even
    return (unsigned short)(u >> 16);
}

__device__ __forceinline__ float fast_tanh(float x) {
    return 1.0f - 2.0f / (__expf(2.0f * x) + 1.0f);
}

__device__ __forceinline__ void gload_lds16(const void* g, void* l) {
    __builtin_amdgcn_global_load_lds(
        (const __attribute__((address_space(1))) unsigned int*)g,
        (__attribute__((address_space(3))) unsigned int*)l, 16, 0, 0);
}

// ---------------------------------------------------------------------------
// prep: one launch doing enc-proj, pred-proj, and W_out transpose+cast.
// Projection: Y[M,640] = X[M,512] @ W[512,640] (+bias), 32x128 tiles,
// 2 rows x 8 cols per thread (w-b128 amortized over 2 rows, a via b128).
// w cols split {c, c+64}: each w-read is 256B contiguous -> 2-way bank = free.
// ---------------------------------------------------------------------------
#define PJ_BM 32
#define PJ_BN 128
#define PJ_BK 32
#define NCB   (JDIM / PJ_BN)          // 5
#define ENC_RB 25                     // 800/32
#define PRED_RB 13                    // ceil(400/32)
#define ENC_BLOCKS  (ENC_RB * NCB)    // 125
#define PRED_BLOCKS (PRED_RB * NCB)   // 65
#define TC_BLOCKS   (20 * 32)         // 640
#define PREP_BLOCKS (ENC_BLOCKS + PRED_BLOCKS + TC_BLOCKS)  // 830

#define XS_LD 36    // 32 k + 4 pad (floats)
#define WS_LD 132   // 128 n + 4 pad (floats)

__global__ __launch_bounds__(256)
void prep(const float* __restrict__ enc_out, const float* __restrict__ pred_out,
          const float* __restrict__ W_enc, const float* __restrict__ b_enc,
          const float* __restrict__ W_pred, const float* __restrict__ W_out,
          float* __restrict__ encp, float* __restrict__ predp,
          unsigned short* __restrict__ Wt)
{
    __shared__ float smem[PJ_BM * XS_LD + PJ_BK * WS_LD];  // 21.5 KB
    const int bid = blockIdx.x;
    const int tid = threadIdx.x;

    if (bid < ENC_BLOCKS + PRED_BLOCKS) {
        // ---- projection branch ----
        const float* X; const float* W; const float* bias; float* Y; int M; int lb;
        if (bid < ENC_BLOCKS) {
            X = enc_out; W = W_enc; bias = b_enc; Y = encp; M = 800; lb = bid;
        } else {
            X = pred_out; W = W_pred; bias = nullptr; Y = predp; M = 400; lb = bid - ENC_BLOCKS;
        }
        const int row0 = (lb / NCB) * PJ_BM;
        const int col0 = (lb % NCB) * PJ_BN;

        float* Xs = smem;                    // [32][36]
        float* Ws = smem + PJ_BM * XS_LD;    // [32][132]

        // staging indices
        const int xr = tid >> 3;             // 0..31
        const int xk = (tid & 7) * 4;        // 0..28
        const int wrow = tid >> 5;           // 0..7 (+8r)
        const int wcol = (tid & 31) * 4;     // 0..124
        // compute indices
        const int ty = tid >> 4;             // 0..15 -> rows ty, ty+16
        const int tx = tid & 15;             // cols tx*4, tx*4+64

        int xrow = row0 + xr; if (xrow >= M) xrow = M - 1;

        float4v acc00 = {0,0,0,0}, acc01 = {0,0,0,0};
        float4v acc10 = {0,0,0,0}, acc11 = {0,0,0,0};

        for (int k0 = 0; k0 < ENC_DIM; k0 += PJ_BK) {
            *(float4v*)&Xs[xr * XS_LD + xk] =
                *(const float4v*)(X + (size_t)xrow * ENC_DIM + k0 + xk);
            #pragma unroll
            for (int r = 0; r < 4; ++r)
                *(float4v*)&Ws[(wrow + 8*r) * WS_LD + wcol] =
                    *(const float4v*)(W + (size_t)(k0 + wrow + 8*r) * JDIM + col0 + wcol);
            __syncthreads();
            #pragma unroll
            for (int k4 = 0; k4 < PJ_BK / 4; ++k4) {
                float4v a0 = *(const float4v*)&Xs[ty * XS_LD + k4*4];
                float4v a1 = *(const float4v*)&Xs[(ty + 16) * XS_LD + k4*4];
                #pragma unroll
                for (int q = 0; q < 4; ++q) {
                    float4v w0 = *(const float4v*)&Ws[(k4*4 + q) * WS_LD + tx*4];
                    float4v w1 = *(const float4v*)&Ws[(k4*4 + q) * WS_LD + tx*4 + 64];
                    float a0q = a0[q], a1q = a1[q];
                    acc00 += w0 * a0q;  acc01 += w1 * a0q;
                    acc10 += w0 * a1q;  acc11 += w1 * a1q;
                }
            }
            __syncthreads();
        }

        const int c0 = col0 + tx*4, c1 = c0 + 64;
        float4v bb0 = {0,0,0,0}, bb1 = {0,0,0,0};
        if (bias) { bb0 = *(const float4v*)(bias + c0); bb1 = *(const float4v*)(bias + c1); }
        int r0 = row0 + ty, r1 = row0 + ty + 16;
        if (r0 < M) {
            *(float4v*)(Y + (size_t)r0 * JDIM + c0) = acc00 + bb0;
            *(float4v*)(Y + (size_t)r0 * JDIM + c1) = acc01 + bb1;
        }
        if (r1 < M) {
            *(float4v*)(Y + (size_t)r1 * JDIM + c0) = acc10 + bb0;
            *(float4v*)(Y + (size_t)r1 * JDIM + c1) = acc11 + bb1;
        }
    } else {
        // ---- transpose+cast branch: Wt[n][k] = bf16(W_out[k][n]) ----
        float (*tile)[33] = (float(*)[33])smem;   // 4.2 KB of the union
        const int local = bid - (ENC_BLOCKS + PRED_BLOCKS);
        const int bk = local % 20;
        const int bn = local / 20;
        const int tx = tid & 31;
        const int ty = tid >> 5;
        #pragma unroll
        for (int i = 0; i < 32; i += 8)
            tile[ty + i][tx] = W_out[(size_t)(bk * 32 + ty + i) * VOCAB + bn * 32 + tx];
        __syncthreads();
        #pragma unroll
        for (int i = 0; i < 32; i += 8)
            Wt[(size_t)(bn * 32 + ty + i) * JDIM + bk * 32 + tx] = f2bf(tile[tx][ty + i]);
    }
}

// ---------------------------------------------------------------------------
// joint_tanh: jbuf[m-m0][k] = bf16(tanh(encp[row(m)][k] + predp[row(m)][k]))
// 8 elems/thread, 16 B stores.
// ---------------------------------------------------------------------------
__global__ __launch_bounds__(256)
void joint_tanh(const float* __restrict__ encp, const float* __restrict__ predp,
                unsigned short* __restrict__ jbuf, int m0, int mcount) {
    int idx = blockIdx.x * 256 + threadIdx.x;
    if (idx >= mcount * (JDIM / 8)) return;
    int m  = idx / (JDIM / 8);
    int c8 = (idx - m * (JDIM / 8)) * 8;
    int mg = m0 + m;
    int b   = mg / (T_ * U_);
    int rem = mg - b * (T_ * U_);
    int t   = rem / U_;
    int u   = rem - t * U_;
    const float* eRow = encp  + (size_t)(b * T_ + t) * JDIM + c8;
    const float* pRow = predp + (size_t)(b * U_ + u) * JDIM + c8;
    float4v e0 = *(const float4v*)(eRow);
    float4v e1 = *(const float4v*)(eRow + 4);
    float4v p0 = *(const float4v*)(pRow);
    float4v p1 = *(const float4v*)(pRow + 4);
    ushort8v v;
    v.s0 = f2bf(fast_tanh(e0.x + p0.x));
    v.s1 = f2bf(fast_tanh(e0.y + p0.y));
    v.s2 = f2bf(fast_tanh(e0.z + p0.z));
    v.s3 = f2bf(fast_tanh(e0.w + p0.w));
    v.s4 = f2bf(fast_tanh(e1.x + p1.x));
    v.s5 = f2bf(fast_tanh(e1.y + p1.y));
    v.s6 = f2bf(fast_tanh(e1.z + p1.z));
    v.s7 = f2bf(fast_tanh(e1.w + p1.w));
    *(ushort8v*)(jbuf + (size_t)m * JDIM + c8) = v;
}

// ---------------------------------------------------------------------------
// Pure bf16 GEMM: out = A @ Wt^T + b_out
// A: [mc,640] bf16 k-contig.  Wt: [1024,640] bf16 k-contig.
// BM=BN=128, BK=64, T3-minimum 2-phase prefetch:
//   STAGE(buf0); vmcnt(0); barrier;
//   loop: STAGE(next->buf^1) FIRST; compute buf; vmcnt(0); barrier; flip.
// Raw s_barrier (NOT __syncthreads: that drains vmcnt before staging overlap).
// Double-buffered LDS 4x16 KB = 64 KB -> still 2 blocks/CU.
// T2 swizzle (BK=64, 8 chunks/row): LDS dest lane-linear, global source
// pre-XOR'd chunk^(row&7), read side same XOR -> ds_read_b128 optimal 8 cyc
// (8 slots x 4 banks = all 32 banks).
// ---------------------------------------------------------------------------
#define GBM 128
#define GBN 128
#define GBK 64
#define NBN (VOCAB / GBN)    // 8
#define NTILES (JDIM / GBK)  // 10

__global__ __launch_bounds__(256, 2)
void gemm_joint(const unsigned short* __restrict__ A,
                const unsigned short* __restrict__ Wt,
                const float* __restrict__ bout,
                float* __restrict__ out)
{
    __shared__ __align__(16) unsigned short As[2][GBM * GBK];  // 2 x 16 KB
    __shared__ __align__(16) unsigned short Bs[2][GBN * GBK];  // 2 x 16 KB

    const int tid = threadIdx.x;

    // XCD-aware swizzle (bijective: gridDim.x = nbm*8, always % 8 == 0).
    const int cpx = gridDim.x >> 3;
    const int bid = blockIdx.x;
    const int swz = (bid & 7) * cpx + (bid >> 3);
    const int bm = swz >> 3;          // NBN == 8
    const int bn = swz & (NBN - 1);

    // staging: 256 thr x 16B = 4 KB/round, 4 rounds cover 128 rows x 64 k.
    // thread -> row (tid>>3)+32r, chunk tid&7; LDS dst = tid*16B + r*4KB (linear).
    const int srow = tid >> 3;        // 0..31
    const int schunk = tid & 7;       // 16B chunk slot
    const int scolSwz = (schunk ^ (srow & 7)) * 8;   // pre-swizzled global chunk
    const unsigned short* aBase = A  + (size_t)(bm * GBM + srow) * JDIM + scolSwz;
    const unsigned short* bBase = Wt + (size_t)(bn * GBN + srow) * JDIM + scolSwz;
    const int ldsOff = tid * 8;       // shorts

    const int wave = tid >> 6, lane = tid & 63;
    const int wm = (wave >> 1) * 64, wn = (wave & 1) * 64;
    const int lm = lane & 15, quad = lane >> 4;
    const int rx = lm & 7;            // row&7 for this lane's fragment rows

    float4v acc[4][4];
    #pragma unroll
    for (int i = 0; i < 4; ++i)
        #pragma unroll
        for (int j = 0; j < 4; ++j)
            acc[i][j] = (float4v){0.f, 0.f, 0.f, 0.f};

#define STAGE(buf, k0)                                                          \
    {                                                                           \
        _Pragma("unroll")                                                       \
        for (int r = 0; r < 4; ++r) {                                           \
            gload_lds16(aBase + (size_t)(r * 32) * JDIM + (k0), &As[buf][ldsOff + r * 2048]); \
            gload_lds16(bBase + (size_t)(r * 32) * JDIM + (k0), &Bs[buf][ldsOff + r * 2048]); \
        }                                                                       \
    }

#define COMPUTE(buf)                                                            \
    {                                                                           \
        _Pragma("unroll")                                                       \
        for (int kk = 0; kk < GBK; kk += 32) {                                  \
            const int cp = (((kk >> 3) + quad) ^ rx) * 8;                       \
            short8 a[4], b[4];                                                  \
            _Pragma("unroll")                                                   \
            for (int i = 0; i < 4; ++i)                                         \
                a[i] = *(const short8*)(&As[buf][(wm + i * 16 + lm) * GBK + cp]); \
            _Pragma("unroll")                                                   \
            for (int j = 0; j < 4; ++j)                                         \
                b[j] = *(const short8*)(&Bs[buf][(wn + j * 16 + lm) * GBK + cp]); \
            _Pragma("unroll")                                                   \
            for (int i = 0; i < 4; ++i)                                         \
                _Pragma("unroll")                                               \
                for (int j = 0; j < 4; ++j)                                     \
                    acc[i][j] = __builtin_amdgcn_mfma_f32_16x16x32_bf16(a[i], b[j], acc[i][j], 0, 0, 0); \
        }                                                                       \
    }

    // prologue
    STAGE(0, 0);
    asm volatile("s_waitcnt vmcnt(0)" ::: "memory");
    __builtin_amdgcn_s_barrier();

    int cur = 0;
    for (int t = 0; t < NTILES - 1; ++t) {
        STAGE(cur ^ 1, (t + 1) * GBK);           // issue next-tile loads FIRST
        COMPUTE(cur);                            // ds_read + MFMA on current
        asm volatile("s_waitcnt vmcnt(0)" ::: "memory");
        __builtin_amdgcn_s_barrier();
        cur ^= 1;
    }
    COMPUTE(cur);                                // last tile (no prefetch)

#undef STAGE
#undef COMPUTE

    #pragma unroll
    for (int j = 0; j < 4; ++j) {
        int ng = bn * GBN + wn + j * 16 + lm;
        float bias = bout[ng];
        #pragma unroll
        for (int i = 0; i < 4; ++i) {
            int mg0 = bm * GBM + wm + i * 16 + quad * 4;
            #pragma unroll
            for (int r = 0; r < 4; ++r)
                __builtin_nontemporal_store(acc[i][j][r] + bias,
                                            out + (size_t)(mg0 + r) * VOCAB + ng);
        }
    }
}

// ---------------------------------------------------------------------------
// Fallback (ws too small): fused kernel — tanh recomputed per N-tile.
// ---------------------------------------------------------------------------
#define BM 128
#define BN 128
#define BK 64
#define LDST 72

__global__ __launch_bounds__(256, 2)
void joint_gemm_fused(const float* __restrict__ encp, const float* __restrict__ predp,
                      const unsigned short* __restrict__ Wt, const float* __restrict__ bout,
                      float* __restrict__ out)
{
    __shared__ __align__(16) unsigned short As[BM * LDST];
    __shared__ __align__(16) unsigned short Bs[BN * LDST];
    const int tid = threadIdx.x;
    const int bm = blockIdx.x, bn = blockIdx.y;
    const int rbase = tid >> 4;
    const int c4 = (tid & 15) * 4;
    int encOff[8], predOff[8];
    #pragma unroll
    for (int i = 0; i < 8; ++i) {
        int mg  = bm * BM + i * 16 + rbase;
        int b   = mg / (T_ * U_);
        int rem = mg - b * (T_ * U_);
        int t   = rem / U_;
        int u   = rem - t * U_;
        encOff[i]  = (b * T_ + t) * JDIM + c4;
        predOff[i] = (b * U_ + u) * JDIM + c4;
    }
    const int nrow = tid >> 3;
    const int bk8  = (tid & 7) * 8;
    const size_t wtBase = (size_t)(bn * BN) * JDIM;
    const int wave = tid >> 6, lane = tid & 63;
    const int wm = (wave >> 1) * 64, wn = (wave & 1) * 64;
    const int lm = lane & 15, quad = lane >> 4;

    float4v acc[4][4];
    #pragma unroll
    for (int i = 0; i < 4; ++i)
        #pragma unroll
        for (int j = 0; j < 4; ++j)
            acc[i][j] = (float4v){0.f, 0.f, 0.f, 0.f};

    for (int k0 = 0; k0 < JDIM; k0 += BK) {
        #pragma unroll
        for (int i = 0; i < 8; ++i) {
            int row = i * 16 + rbase;
            float4v e4 = *(const float4v*)(encp + encOff[i] + k0);
            float4v p4 = *(const float4v*)(predp + predOff[i] + k0);
            ushort4v v;
            v.x = f2bf(fast_tanh(e4.x + p4.x));
            v.y = f2bf(fast_tanh(e4.y + p4.y));
            v.z = f2bf(fast_tanh(e4.z + p4.z));
            v.w = f2bf(fast_tanh(e4.w + p4.w));
            *(ushort4v*)(&As[row * LDST + c4]) = v;
        }
        #pragma unroll
        for (int i = 0; i < 4; ++i) {
            int n = i * 32 + nrow;
            float4v w = *(const float4v*)((const float*)(Wt + wtBase + (size_t)n * JDIM + k0 + bk8));
            *(float4v*)(&Bs[n * LDST + bk8]) = w;
        }
        __syncthreads();
        #pragma unroll
        for (int kk = 0; kk < BK; kk += 32) {
            short8 a[4], b[4];
            #pragma unroll
            for (int i = 0; i < 4; ++i)
                a[i] = *(const short8*)(&As[(wm + i * 16 + lm) * LDST + kk + quad * 8]);
            #pragma unroll
            for (int j = 0; j < 4; ++j)
                b[j] = *(const short8*)(&Bs[(wn + j * 16 + lm) * LDST + kk + quad * 8]);
            #pragma unroll
            for (int i = 0; i < 4; ++i)
                #pragma unroll
                for (int j = 0; j < 4; ++j)
                    acc[i][j] = __builtin_amdgcn_mfma_f32_16x16x32_bf16(a[i], b[j], acc[i][j], 0, 0, 0);
        }
        __syncthreads();
    }
    #pragma unroll
    for (int j = 0; j < 4; ++j) {
        int ng = bn * BN + wn + j * 16 + lm;
        float bias = bout[ng];
        #pragma unroll
        for (int i = 0; i < 4; ++i) {
            int mg0 = bm * BM + wm + i * 16 + quad * 4;
            #pragma unroll
            for (int r = 0; r < 4; ++r)
                out[(size_t)(mg0 + r) * VOCAB + ng] = acc[i][j][r] + bias;
        }
    }
}

// ---------------------------------------------------------------------------
extern "C" void kernel_launch(void* const* d_in, const int* in_sizes, int n_in,
                              void* d_out, int out_size, void* d_ws, size_t ws_size,
                              hipStream_t stream) {
    const float* enc_out  = (const float*)d_in[0];  // [4,200,512]
    const float* pred_out = (const float*)d_in[1];  // [4,100,512]
    const float* W_enc    = (const float*)d_in[2];  // [512,640]
    const float* b_enc    = (const float*)d_in[3];  // [640]
    const float* W_pred   = (const float*)d_in[4];  // [512,640]
    const float* W_out    = (const float*)d_in[5];  // [640,1024]
    const float* b_out    = (const float*)d_in[6];  // [1024]
    float* out = (float*)d_out;

    float* encp  = (float*)d_ws;                                 // 800*640 fp32
    float* predp = encp + 800 * JDIM;                            // 400*640 fp32
    unsigned short* Wt = (unsigned short*)(predp + 400 * JDIM);  // 1024*640 bf16
    unsigned short* jbuf = Wt + (size_t)VOCAB * JDIM;            // chunked joint bf16

    const size_t fixedBytes = (800 * JDIM + 400 * JDIM) * sizeof(float)
                            + (size_t)VOCAB * JDIM * sizeof(unsigned short);

    prep<<<dim3(PREP_BLOCKS), 256, 0, stream>>>(enc_out, pred_out, W_enc, b_enc,
                                                W_pred, W_out, encp, predp, Wt);

    size_t avail = ws_size > fixedBytes ? ws_size - fixedBytes : 0;
    long mcMax = (long)(avail / (JDIM * sizeof(unsigned short)));
    mcMax = (mcMax / 128) * 128;
    if (mcMax > M_TOTAL) mcMax = M_TOTAL;

    if (mcMax >= 8192) {
        for (int m0 = 0; m0 < M_TOTAL; m0 += (int)mcMax) {
            int mc = M_TOTAL - m0 < mcMax ? M_TOTAL - m0 : (int)mcMax;  // always mult of 128
            int nThreads = mc * (JDIM / 8);
            joint_tanh<<<(nThreads + 255) / 256, 256, 0, stream>>>(encp, predp, jbuf, m0, mc);
            gemm_joint<<<dim3((mc / GBM) * NBN), 256, 0, stream>>>(jbuf, Wt, b_out,
                                                                   out + (size_t)m0 * VOCAB);
        }
    } else {
        // scratch too small for materialization — fused path
        joint_gemm_fused<<<dim3(M_TOTAL / BM, VOCAB / BN), 256, 0, stream>>>(encp, predp, Wt, b_out, out);
    }
}